// Round 3
// baseline (1064.127 us; speedup 1.0000x reference)
//
#include <hip/hip_runtime.h>

// GoL CNN v4: layer GEMM M=32(co) x N=64/block x K=CIN*1024, mfma_f32_32x32x16_f16.
// B rows staged into 4 dword-shifted LDS copies -> every B-frag = 1 aligned
// ds_read_b128. Wave w owns ky 4w..4w+3 so pair1 reuses pair0's rows (12 frags
// not 16). Channel-groups of 2, double-buffered, A prefetched a group ahead.

typedef _Float16 f16;
typedef _Float16 f16x8 __attribute__((ext_vector_type(8)));
typedef float f32x4 __attribute__((ext_vector_type(4)));
typedef float f32x16 __attribute__((ext_vector_type(16)));

__device__ __forceinline__ int mwrap(int j) {
  int t = j - 31;
  if ((unsigned)t <= 31u) return t;
  if (t < 0) return (j & 1) ? 0 : 31;
  return (j & 1) ? 0 : 31;
}

// LDS strides in f16 units
#define PLANE 3080   // copy-plane: 32 rows * 96 + 8 pad (de-alias banks)
#define CHST 12320   // 4 * PLANE
#define BUFST 24640  // 2 * CHST

template <int CIN, bool RELU, bool PRE>
__global__ __launch_bounds__(512, 2) void gemm4(
    const void* __restrict__ Wv, const f16* __restrict__ hp_in,
    const float* __restrict__ bias, f16* __restrict__ hp_out) {
  __shared__ __align__(16) char smem[98560];  // Sw (2 bufs) ; Red aliased after
  f16* Sw = (f16*)smem;
  float* Red = (float*)smem;

  const int tid = threadIdx.x;
  const int lane = tid & 63;
  const int w = tid >> 6;      // wave: ky in {4w..4w+3}
  const int ox = lane & 31;    // B n / A m(co)
  const int s = lane >> 5;
  const int pair0 = blockIdx.x * 2;
  const int b = pair0 >> 5;
  const int oy0 = pair0 & 31;  // even

  // B-frag geometry: dwords bi..bi+3, bi = ox+4s(+8 for kxh=1); same copy-plane
  const int bi0 = ox + 4 * s;
  const int r = (4 - (bi0 & 3)) & 3;
  const int m0 = (bi0 + r) >> 2;
  int fragOff[6];
#pragma unroll
  for (int t = 0; t < 6; ++t)
    fragOff[t] = r * PLANE + mwrap(2 * oy0 + 4 * w + t) * 96 + m0 * 8;

  // staging decode: 3072 units = [ch2][copy4][y32][u12], 6 per thread
  int stgLds[6], stgG[6], stgCh[6];
#pragma unroll
  for (int k = 0; k < 6; ++k) {
    const int id = k * 512 + tid;
    const int ch = id / 1536, rem = id - ch * 1536;
    const int cp = rem / 384, rem2 = rem - cp * 384;
    const int y = rem2 / 12, u = rem2 - y * 12;
    stgCh[k] = ch;
    stgLds[k] = ch * CHST + cp * PLANE + y * 96 + u * 8;
    stgG[k] = ch * 3072 + y * 96 + (u * 8 - cp * 2);  // may be -6
  }
  const f16* gbase = hp_in + (size_t)b * CIN * 3072;

  f32x16 acc0 = {}, acc1 = {};
  f16x8 Ac[2][8], An[2][8];
  int stgi[6][4];

  auto loadA = [&](int c, f16x8(&dst)[8]) {
    if constexpr (PRE) {
      const f16* base = (const f16*)Wv + (size_t)(c * 64 + 8 * w) * 512 + lane * 8;
#pragma unroll
      for (int u = 0; u < 8; ++u) dst[u] = *(const f16x8*)(base + u * 512);
    } else {
      const float* W = (const float*)Wv;
#pragma unroll
      for (int i = 0; i < 4; ++i)
#pragma unroll
        for (int kxh = 0; kxh < 2; ++kxh) {
          const float* sp =
              W + ((size_t)(ox * CIN + c) * 32 + (4 * w + i)) * 32 + kxh * 16 + s * 8;
          f32x4 u0 = *(const f32x4*)sp;
          f32x4 u1 = *(const f32x4*)(sp + 4);
          f16x8 v;
          v[0] = (f16)u0[0]; v[1] = (f16)u0[1]; v[2] = (f16)u0[2]; v[3] = (f16)u0[3];
          v[4] = (f16)u1[0]; v[5] = (f16)u1[1]; v[6] = (f16)u1[2]; v[7] = (f16)u1[3];
          dst[i * 2 + kxh] = v;
        }
    }
  };
  auto loadStg = [&](int c0) {
    const f16* gp = gbase + (size_t)c0 * 3072;
#pragma unroll
    for (int k = 0; k < 6; ++k)
      if (c0 + stgCh[k] < CIN) {
#pragma unroll
        for (int d = 0; d < 4; ++d) stgi[k][d] = *(const int*)(gp + stgG[k] + 2 * d);
      }
  };
  auto writeStg = [&](int buf) {
#pragma unroll
    for (int k = 0; k < 6; ++k) {
      int4 v;
      v.x = stgi[k][0]; v.y = stgi[k][1]; v.z = stgi[k][2]; v.w = stgi[k][3];
      *(int4*)(Sw + buf * BUFST + stgLds[k]) = v;
    }
  };
  auto compute = [&](int buf, f16x8(&A)[8], int ch) {
    const f16* Sb = Sw + buf * BUFST + ch * CHST;
#pragma unroll
    for (int kxh = 0; kxh < 2; ++kxh) {
      f16x8 F[6];
#pragma unroll
      for (int t = 0; t < 6; ++t) F[t] = *(const f16x8*)(Sb + fragOff[t] + kxh * 16);
#pragma unroll
      for (int i = 0; i < 4; ++i) {
        acc0 = __builtin_amdgcn_mfma_f32_32x32x16_f16(A[i * 2 + kxh], F[i], acc0, 0, 0, 0);
        acc1 = __builtin_amdgcn_mfma_f32_32x32x16_f16(A[i * 2 + kxh], F[i + 2], acc1, 0, 0, 0);
      }
    }
  };

  constexpr int G = (CIN + 1) / 2;
  loadA(0, Ac[0]);
  if (CIN > 1) loadA(1, Ac[1]);
  loadStg(0);
  writeStg(0);
  __syncthreads();

  for (int g = 0; g < G; ++g) {
    const int buf = g & 1;
    if (g + 1 < G) {
      loadA(2 * g + 2, An[0]);
      loadA(2 * g + 3, An[1]);
      loadStg(2 * g + 2);
    }
    compute(buf, Ac[0], 0);
    if (2 * g + 1 < CIN) compute(buf, Ac[1], 1);
    if (g + 1 < G) {
      writeStg(buf ^ 1);
#pragma unroll
      for (int ch = 0; ch < 2; ++ch)
#pragma unroll
        for (int u = 0; u < 8; ++u) Ac[ch][u] = An[ch][u];
    }
    __syncthreads();
  }

  // 8-way K reduction through LDS (aliases Sw; loop ended with barrier)
#pragma unroll
  for (int rr = 0; rr < 16; ++rr) {
    Red[w * 2048 + rr * 64 + lane] = acc0[rr];
    Red[w * 2048 + 1024 + rr * 64 + lane] = acc1[rr];
  }
  __syncthreads();

#pragma unroll
  for (int k4 = 0; k4 < 4; ++k4) {
    const int o = tid + 512 * k4;  // [p][co][ox]
    const int p = o >> 10, co = (o >> 5) & 31, oxx = o & 31;
    const int idx = ((co & 3) + 4 * (co >> 3)) * 64 + ((co >> 2) & 1) * 32 + oxx;
    float v = bias[co];
#pragma unroll
    for (int w8 = 0; w8 < 8; ++w8) v += Red[w8 * 2048 + p * 1024 + idx];
    if (RELU) v = fmaxf(v, 0.f);
    const f16 hv = (f16)v;
    f16* base = hp_out + ((size_t)(b * 32 + co) * 32 + (oy0 + p)) * 96;
    base[oxx + 31] = hv;
    if (oxx == 0) {
#pragma unroll
      for (int j = 1; j <= 29; j += 2) base[j] = hv;
#pragma unroll
      for (int j = 63; j <= 93; j += 2) base[j] = hv;
    }
    if (oxx == 31) {
#pragma unroll
      for (int j = 0; j <= 30; j += 2) base[j] = hv;
#pragma unroll
      for (int j = 64; j <= 92; j += 2) base[j] = hv;
    }
  }
}

__global__ void pad_x_kernel(const float* __restrict__ x, f16* __restrict__ xp) {
  const int i = blockIdx.x * 256 + threadIdx.x;  // 16*32*94
  if (i >= 48128) return;
  const int bq = i / 3008, r = i - bq * 3008;
  const int y = r / 94, j = r - y * 94;
  xp[bq * 3072 + y * 96 + j] = (f16)x[(bq * 32 + y) * 32 + mwrap(j)];
}

__global__ void convert_w3(const float* __restrict__ in_w,
                           const float* __restrict__ convs_w,
                           f16* __restrict__ WfIn, f16* __restrict__ WfH) {
  const int total = 4096 + 20 * 131072;
  for (int g = blockIdx.x * blockDim.x + threadIdx.x; g < total;
       g += gridDim.x * blockDim.x) {
    const float* src;
    f16* dst;
    int chunk, lanE, c, ky, kxh;
    if (g < 4096) {
      chunk = g >> 6; lanE = g & 63;
      kxh = chunk & 1; ky = chunk >> 1; c = 0;
      const int co = lanE & 31, ss = lanE >> 5;
      src = in_w + ((size_t)co * 32 + ky) * 32 + kxh * 16 + ss * 8;
      dst = WfIn + (size_t)chunk * 512 + lanE * 8;
    } else {
      const int h = g - 4096;
      const int layer = h >> 17, r = h & 131071;
      chunk = r >> 6; lanE = r & 63;
      kxh = chunk & 1;
      const int t = chunk >> 1;
      ky = t & 31; c = t >> 5;
      const int co = lanE & 31, ss = lanE >> 5;
      src = convs_w + (size_t)layer * 1048576 +
            ((size_t)(co * 32 + c) * 32 + ky) * 32 + kxh * 16 + ss * 8;
      dst = WfH + (size_t)layer * 1048576 + (size_t)chunk * 512 + lanE * 8;
    }
    f32x4 u0 = *(const f32x4*)src;
    f32x4 u1 = *(const f32x4*)(src + 4);
    f16x8 v;
    v[0] = (f16)u0[0]; v[1] = (f16)u0[1]; v[2] = (f16)u0[2]; v[3] = (f16)u0[3];
    v[4] = (f16)u1[0]; v[5] = (f16)u1[1]; v[6] = (f16)u1[2]; v[7] = (f16)u1[3];
    *(f16x8*)dst = v;
  }
}

__global__ void out_conv3(const f16* __restrict__ hp,
                          const float* __restrict__ ow,
                          const float* __restrict__ ob,
                          float* __restrict__ out) {
  const int o = blockIdx.x * 256 + threadIdx.x;  // 16384
  const int b = o >> 10, oy = (o >> 5) & 31, oxx = o & 31;
  float s = ob[0];
#pragma unroll
  for (int c = 0; c < 32; ++c)
    s += ow[c] * (float)hp[((size_t)(b * 32 + c) * 32 + oy) * 96 + oxx + 31];
  out[o] = s;
}

extern "C" void kernel_launch(void* const* d_in, const int* in_sizes, int n_in,
                              void* d_out, int out_size, void* d_ws,
                              size_t ws_size, hipStream_t stream) {
  const float* x = (const float*)d_in[0];
  const float* in_w = (const float*)d_in[1];
  const float* in_b = (const float*)d_in[2];
  const float* convs_w = (const float*)d_in[3];
  const float* convs_b = (const float*)d_in[4];
  const float* out_w = (const float*)d_in[5];
  const float* out_b = (const float*)d_in[6];
  float* out = (float*)d_out;

  char* ws = (char*)d_ws;
  f16* xpad = (f16*)(ws + 256);                    //    98,304 B (+256 guard)
  f16* hpA = (f16*)(ws + 256 + 98304);             // 3,145,728 B
  f16* hpB = (f16*)(ws + 256 + 98304 + 3145728);   // 3,145,728 B
  f16* WfIn = (f16*)(ws + 6390016);                //    65,536 B
  f16* WfH = (f16*)(ws + 6455552);                 // 41,943,040 B
  const bool pre = (ws_size >= 48398592ull);

  pad_x_kernel<<<188, 256, 0, stream>>>(x, xpad);
  if (pre) convert_w3<<<2048, 256, 0, stream>>>(in_w, convs_w, WfIn, WfH);

  if (pre)
    gemm4<1, false, true><<<256, 512, 0, stream>>>(WfIn, xpad, in_b, hpA);
  else
    gemm4<1, false, false><<<256, 512, 0, stream>>>(in_w, xpad, in_b, hpA);

  for (int l = 0; l < 20; ++l) {
    const f16* cur = (l % 2 == 0) ? hpA : hpB;
    f16* nxt = (l % 2 == 0) ? hpB : hpA;
    if (pre)
      gemm4<32, true, true><<<256, 512, 0, stream>>>(
          WfH + (size_t)l * 1048576, cur, convs_b + 32 * l, nxt);
    else
      gemm4<32, true, false><<<256, 512, 0, stream>>>(
          convs_w + (size_t)l * 1048576, cur, convs_b + 32 * l, nxt);
  }

  out_conv3<<<64, 256, 0, stream>>>(hpA, out_w, out_b, out);
}